// Round 4
// baseline (298.183 us; speedup 1.0000x reference)
//
#include <hip/hip_runtime.h>

#define N_NODES 100000
#define N_EDGES 1600000

#define NPB   256                      // nodes per bucket
#define NB    391                      // ceil(100000/256)
#define PCAP  8192                     // pairs capacity per bucket (mean ~4096+padding)
#define SCAP  24                       // LDS staging slots per bucket
#define ABLK  128                      // phase-A blocks
#define BATCH 1024                     // edges per block-iteration in phase A

// ---------------- Phase A: bucket edges with line-granular flushes ----------------
// pair = (src<<8) | (dst & 255); bucket = dst >> 8; sentinel = -1
__global__ __launch_bounds__(256) void bucket_kernel(
    const int* __restrict__ src, const int* __restrict__ dst,
    int* __restrict__ tail, int* __restrict__ pairs, int E) {
    __shared__ int lcnt[NB];
    __shared__ int stage[NB * SCAP];
    const int tid = threadIdx.x;
    for (int b = tid; b < NB; b += 256) lcnt[b] = 0;
    __syncthreads();

    const int chunk = (E + gridDim.x - 1) / gridDim.x;   // 12500
    const int e0 = blockIdx.x * chunk;
    const int e1 = min(e0 + chunk, E);

    for (int be = e0; be < e1; be += BATCH) {
        // append: 4 edges per thread
#pragma unroll
        for (int q = 0; q < 4; ++q) {
            int e = be + q * 256 + tid;
            if (e < e1) {
                int d = dst[e];
                int p = (src[e] << 8) | (d & 255);
                int b = d >> 8;
                int pos = atomicAdd(&lcnt[b], 1);
                if (pos < SCAP) {
                    stage[b * SCAP + pos] = p;
                } else {
                    // overflow fallback (~never): grab a full aligned group, pad with sentinels
                    int g = atomicAdd(&tail[b], 8);
                    if (g + 8 <= PCAP) {
                        pairs[b * PCAP + g] = p;
                        for (int j = 1; j < 8; ++j) pairs[b * PCAP + g + j] = -1;
                    }
                }
            }
        }
        __syncthreads();
        // flush full groups of 8 (32B, aligned; each line chunk owned by this block)
        for (int b = tid; b < NB; b += 256) {
            int n = min(lcnt[b], SCAP);
            int ng = n >> 3;
            if (ng) {
                int base = atomicAdd(&tail[b], ng * 8);
                int4* gdst = (int4*)(pairs + b * PCAP + base);
                int4* lsrc = (int4*)(stage + b * SCAP);
                for (int g = 0; g < ng; ++g) {
                    if (base + g * 8 + 8 <= PCAP) {
                        gdst[g * 2]     = lsrc[g * 2];
                        gdst[g * 2 + 1] = lsrc[g * 2 + 1];
                    }
                }
                int rem = n & 7;
                for (int j = 0; j < rem; ++j) stage[b * SCAP + j] = stage[b * SCAP + ng * 8 + j];
                lcnt[b] = rem;
            } else {
                lcnt[b] = n;   // clamp if overflowed
            }
        }
        __syncthreads();
    }
    // final flush: pad remainder to a full group with sentinels
    for (int b = tid; b < NB; b += 256) {
        int n = min(lcnt[b], SCAP);
        if (n) {
            int ng = (n + 7) >> 3;
            for (int j = n; j < ng * 8; ++j) stage[b * SCAP + j] = -1;
            int base = atomicAdd(&tail[b], ng * 8);
            int4* gdst = (int4*)(pairs + b * PCAP + base);
            int4* lsrc = (int4*)(stage + b * SCAP);
            for (int g = 0; g < ng; ++g) {
                if (base + g * 8 + 8 <= PCAP) {
                    gdst[g * 2]     = lsrc[g * 2];
                    gdst[g * 2 + 1] = lsrc[g * 2 + 1];
                }
            }
        }
    }
}

// ---------------- B0: per-bucket in-degree -> dinv + pre-scaled xs12 ----------------
__global__ __launch_bounds__(1024) void count_kernel(
    const int* __restrict__ tail, const int* __restrict__ pairs,
    const float* __restrict__ x, float* __restrict__ dinv,
    float* __restrict__ xs12, int N) {
    __shared__ int cnt[NPB];
    const int b = blockIdx.x, tid = threadIdx.x;
    if (tid < NPB) cnt[tid] = 0;
    __syncthreads();
    const int n = min(tail[b], PCAP);
    const int* pb = pairs + b * PCAP;
    for (int i = tid; i < n; i += 1024) {
        int p = pb[i];
        if (p >= 0) atomicAdd(&cnt[p & 255], 1);
    }
    __syncthreads();
    if (tid < NPB) {
        int node = b * NPB + tid;
        if (node < N) {
            float di = rsqrtf((float)cnt[tid] + 1.0f);
            dinv[node] = di;
#pragma unroll
            for (int k = 0; k < 10; ++k) xs12[node * 12 + k] = x[node * 10 + k] * di;
        }
    }
}

// ---------------- B1/B2: per-bucket gather-aggregate in LDS ----------------
// out10[n][c] = val12[n][c] (self) + sum_{(s,n) in bucket pairs} val12[s][c]
__global__ __launch_bounds__(1024) void agg_kernel(
    const int* __restrict__ tail, const int* __restrict__ pairs,
    const float* __restrict__ val12, float* __restrict__ out10, int N) {
    __shared__ float acc[NPB * 10];
    const int b = blockIdx.x, tid = threadIdx.x;
    for (int i = tid; i < NPB * 10; i += 1024) acc[i] = 0.f;
    __syncthreads();
    const int n = min(tail[b], PCAP);
    const int* pb = pairs + b * PCAP;
    for (int i = tid; i < n; i += 1024) {
        int p = pb[i];
        if (p >= 0) {
            int s = p >> 8;
            int dl = p & 255;
            const float4* v = (const float4*)(val12 + (size_t)s * 12);
            float4 a0 = v[0], a1 = v[1], a2 = v[2];
            float* a = acc + dl * 10;
            atomicAdd(a + 0, a0.x); atomicAdd(a + 1, a0.y);
            atomicAdd(a + 2, a0.z); atomicAdd(a + 3, a0.w);
            atomicAdd(a + 4, a1.x); atomicAdd(a + 5, a1.y);
            atomicAdd(a + 6, a1.z); atomicAdd(a + 7, a1.w);
            atomicAdd(a + 8, a2.x); atomicAdd(a + 9, a2.y);
        }
    }
    __syncthreads();
    const int node0 = b * NPB;
    for (int idx = tid; idx < NPB * 10; idx += 1024) {
        int local = idx / 10;
        int c = idx - local * 10;
        int node = node0 + local;
        if (node < N) out10[(size_t)node * 10 + c] = acc[idx] + val12[(size_t)node * 12 + c];
    }
}

// ---------------- fused MLP: ax = dinv*agg ; y = relu(ax@W1+b1) ; t12 = (y@W2)*dinv ----------------
__global__ void layer12_kernel(const float* __restrict__ agg, const float* __restrict__ dinv,
                               const float* __restrict__ W1, const float* __restrict__ b1,
                               const float* __restrict__ W2, float* __restrict__ t12, int N) {
    __shared__ float sW1[640];
    __shared__ float sW2[640];
    __shared__ float sb1[64];
    for (int k = threadIdx.x; k < 640; k += blockDim.x) { sW1[k] = W1[k]; sW2[k] = W2[k]; }
    if (threadIdx.x < 64) sb1[threadIdx.x] = b1[threadIdx.x];
    __syncthreads();
    int i = blockIdx.x * blockDim.x + threadIdx.x;
    if (i >= N) return;
    float di = dinv[i];
    float ax[10];
#pragma unroll
    for (int k = 0; k < 10; ++k) ax[k] = di * agg[(size_t)i * 10 + k];
    float o[10];
#pragma unroll
    for (int k = 0; k < 10; ++k) o[k] = 0.f;
    for (int c = 0; c < 64; ++c) {
        float y = sb1[c];
#pragma unroll
        for (int k = 0; k < 10; ++k) y = fmaf(ax[k], sW1[k * 64 + c], y);
        y = fmaxf(y, 0.f);
#pragma unroll
        for (int k = 0; k < 10; ++k) o[k] = fmaf(y, sW2[c * 10 + k], o[k]);
    }
#pragma unroll
    for (int k = 0; k < 10; ++k) t12[(size_t)i * 12 + k] = o[k] * di;
}

// ---------------- final: v = dinv*agg2 + b2 ; out = log_softmax(v) ----------------
__global__ void final_kernel(const float* __restrict__ agg2, const float* __restrict__ dinv,
                             const float* __restrict__ b2, float* __restrict__ out, int N) {
    int i = blockIdx.x * blockDim.x + threadIdx.x;
    if (i >= N) return;
    float di = dinv[i];
    float v[10];
    float m = -1e30f;
#pragma unroll
    for (int c = 0; c < 10; ++c) {
        float u = di * agg2[(size_t)i * 10 + c] + b2[c];
        v[c] = u;
        m = fmaxf(m, u);
    }
    float s = 0.f;
#pragma unroll
    for (int c = 0; c < 10; ++c) s += __expf(v[c] - m);
    float lse = __logf(s);
#pragma unroll
    for (int c = 0; c < 10; ++c) out[(size_t)i * 10 + c] = v[c] - m - lse;
}

extern "C" void kernel_launch(void* const* d_in, const int* in_sizes, int n_in,
                              void* d_out, int out_size, void* d_ws, size_t ws_size,
                              hipStream_t stream) {
    const float* x  = (const float*)d_in[0];
    const int*   ei = (const int*)d_in[1];
    const float* W1 = (const float*)d_in[2];
    const float* b1 = (const float*)d_in[3];
    const float* W2 = (const float*)d_in[4];
    const float* b2 = (const float*)d_in[5];
    float* out = (float*)d_out;

    const int N = N_NODES, E = N_EDGES;
    const int* src = ei;
    const int* dst = ei + E;

    // ws: [tail pad->512 ints][pairs NB*PCAP ints][dinv N][xs12 N*12][agg N*10][t12 N*12][agg2 N*10]
    int*   tail  = (int*)d_ws;
    int*   pairs = tail + 512;                       // 2048B offset -> 16B aligned
    float* dinv  = (float*)(pairs + (size_t)NB * PCAP);
    float* xs12  = dinv + N;
    float* agg   = xs12 + (size_t)N * 12;
    float* t12   = agg  + (size_t)N * 10;
    float* agg2  = t12  + (size_t)N * 12;

    hipMemsetAsync(tail, 0, sizeof(int) * NB, stream);

    bucket_kernel<<<ABLK, 256, 0, stream>>>(src, dst, tail, pairs, E);
    count_kernel<<<NB, 1024, 0, stream>>>(tail, pairs, x, dinv, xs12, N);
    agg_kernel<<<NB, 1024, 0, stream>>>(tail, pairs, xs12, agg, N);
    layer12_kernel<<<(N + 255) / 256, 256, 0, stream>>>(agg, dinv, W1, b1, W2, t12, N);
    agg_kernel<<<NB, 1024, 0, stream>>>(tail, pairs, t12, agg2, N);
    final_kernel<<<(N + 255) / 256, 256, 0, stream>>>(agg2, dinv, b2, out, N);
}

// Round 5
// 122.419 us; speedup vs baseline: 2.4358x; 2.4358x over previous
//
#include <hip/hip_runtime.h>

#define N_NODES 100000
#define N_EDGES 1600000

#define NPB   256                      // nodes per bucket
#define NB    391                      // ceil(100000/256)
#define PCAP  8192                     // pairs capacity per bucket
#define SCAP  24                       // LDS staging slots per bucket
#define ABLK  256                      // phase-A blocks
#define BATCH 1024                     // edges per block-iteration in phase A
#define CAP   64                       // per-node CSR row capacity

// ---------------- Phase A: bucket edges with line-granular flushes ----------------
// pair = (src<<8) | (dst & 255); bucket = dst >> 8; sentinel = -1
__global__ __launch_bounds__(256) void bucket_kernel(
    const int* __restrict__ src, const int* __restrict__ dst,
    int* __restrict__ tail, int* __restrict__ pairs, int E) {
    __shared__ int lcnt[NB];
    __shared__ int stage[NB * SCAP];
    const int tid = threadIdx.x;
    for (int b = tid; b < NB; b += 256) lcnt[b] = 0;
    __syncthreads();

    const int chunk = (E + gridDim.x - 1) / gridDim.x;
    const int e0 = blockIdx.x * chunk;
    const int e1 = min(e0 + chunk, E);

    for (int be = e0; be < e1; be += BATCH) {
#pragma unroll
        for (int q = 0; q < 4; ++q) {
            int e = be + q * 256 + tid;
            if (e < e1) {
                int d = dst[e];
                int p = (src[e] << 8) | (d & 255);
                int b = d >> 8;
                int pos = atomicAdd(&lcnt[b], 1);
                if (pos < SCAP) {
                    stage[b * SCAP + pos] = p;
                } else {
                    int g = atomicAdd(&tail[b], 8);
                    if (g + 8 <= PCAP) {
                        pairs[b * PCAP + g] = p;
                        for (int j = 1; j < 8; ++j) pairs[b * PCAP + g + j] = -1;
                    }
                }
            }
        }
        __syncthreads();
        for (int b = tid; b < NB; b += 256) {
            int n = min(lcnt[b], SCAP);
            int ng = n >> 3;
            if (ng) {
                int base = atomicAdd(&tail[b], ng * 8);
                int4* gdst = (int4*)(pairs + b * PCAP + base);
                int4* lsrc = (int4*)(stage + b * SCAP);
                for (int g = 0; g < ng; ++g) {
                    if (base + g * 8 + 8 <= PCAP) {
                        gdst[g * 2]     = lsrc[g * 2];
                        gdst[g * 2 + 1] = lsrc[g * 2 + 1];
                    }
                }
                int rem = n & 7;
                for (int j = 0; j < rem; ++j) stage[b * SCAP + j] = stage[b * SCAP + ng * 8 + j];
                lcnt[b] = rem;
            } else {
                lcnt[b] = n;
            }
        }
        __syncthreads();
    }
    for (int b = tid; b < NB; b += 256) {
        int n = min(lcnt[b], SCAP);
        if (n) {
            int ng = (n + 7) >> 3;
            for (int j = n; j < ng * 8; ++j) stage[b * SCAP + j] = -1;
            int base = atomicAdd(&tail[b], ng * 8);
            int4* gdst = (int4*)(pairs + b * PCAP + base);
            int4* lsrc = (int4*)(stage + b * SCAP);
            for (int g = 0; g < ng; ++g) {
                if (base + g * 8 + 8 <= PCAP) {
                    gdst[g * 2]     = lsrc[g * 2];
                    gdst[g * 2 + 1] = lsrc[g * 2 + 1];
                }
            }
        }
    }
}

// ---------------- Phase B: per-bucket pairs -> CSR rows (block-private 64KB region) ----------------
// slist[node*CAP + pos] = src ; cnt[node] = deg ; zero-pad each row to multiple of 4
__global__ __launch_bounds__(1024) void csr_kernel(
    const int* __restrict__ tail, const int* __restrict__ pairs,
    int* __restrict__ cnt, int* __restrict__ slist, int N) {
    __shared__ int ofs[NPB];
    const int b = blockIdx.x, tid = threadIdx.x;
    if (tid < NPB) ofs[tid] = 0;
    __syncthreads();
    const int n = min(tail[b], PCAP);
    const int* pb = pairs + b * PCAP;
    const int node0 = b * NPB;
    for (int i = tid; i < n; i += 1024) {
        int p = pb[i];
        if (p >= 0) {
            int dl = p & 255;
            int pos = atomicAdd(&ofs[dl], 1);
            if (pos < CAP) slist[(size_t)(node0 + dl) * CAP + pos] = p >> 8;
        }
    }
    __syncthreads();
    if (tid < NPB) {
        int node = node0 + tid;
        if (node < N) {
            int deg = min(ofs[tid], CAP);
            cnt[node] = deg;
            int padded = (deg + 3) & ~3;
            for (int j = deg; j < padded; ++j) slist[(size_t)node * CAP + j] = 0;
        }
    }
}

// dinv[i] = rsqrt(deg+1); xs[i][c] = x[i][c] * dinv[i]
__global__ void dinv_xs_kernel(const float* __restrict__ x, const int* __restrict__ cnt,
                               float* __restrict__ dinv, float* __restrict__ xs, int N) {
    int i = blockIdx.x * blockDim.x + threadIdx.x;
    if (i >= N) return;
    float di = rsqrtf((float)cnt[i] + 1.0f);
    dinv[i] = di;
#pragma unroll
    for (int c = 0; c < 10; ++c) xs[i * 10 + c] = x[i * 10 + c] * di;
}

// out[i][c] = val[i][c] (self-loop) + sum_{s in in(i)} val[s][c]
// 10 threads per node; int4 edge-list loads; row padding entries are 0.
__global__ void agg_kernel(const float* __restrict__ val, const int* __restrict__ cnt,
                           const int* __restrict__ slist, float* __restrict__ out, int N) {
    int gt = blockIdx.x * blockDim.x + threadIdx.x;
    int i = gt / 10;
    int c = gt - i * 10;
    if (i >= N) return;
    int degi = cnt[i];
    const int* lst = slist + (size_t)i * CAP;
    float a = val[i * 10 + c];
    for (int k = 0; k < degi; k += 4) {
        int4 s4 = *reinterpret_cast<const int4*>(lst + k);
        float v0 = val[s4.x * 10 + c];
        float v1 = val[s4.y * 10 + c];
        float v2 = val[s4.z * 10 + c];
        float v3 = val[s4.w * 10 + c];
        a += v0;
        a += (k + 1 < degi) ? v1 : 0.f;
        a += (k + 2 < degi) ? v2 : 0.f;
        a += (k + 3 < degi) ? v3 : 0.f;
    }
    out[i * 10 + c] = a;
}

// ax = dinv*agg ; y = relu(ax@W1 + b1) ; t = (y@W2)*dinv
__global__ void layer12_kernel(const float* __restrict__ agg, const float* __restrict__ dinv,
                               const float* __restrict__ W1, const float* __restrict__ b1,
                               const float* __restrict__ W2, float* __restrict__ t, int N) {
    __shared__ float sW1[640];
    __shared__ float sW2[640];
    __shared__ float sb1[64];
    for (int k = threadIdx.x; k < 640; k += blockDim.x) { sW1[k] = W1[k]; sW2[k] = W2[k]; }
    if (threadIdx.x < 64) sb1[threadIdx.x] = b1[threadIdx.x];
    __syncthreads();
    int i = blockIdx.x * blockDim.x + threadIdx.x;
    if (i >= N) return;
    float di = dinv[i];
    float ax[10];
#pragma unroll
    for (int k = 0; k < 10; ++k) ax[k] = di * agg[i * 10 + k];
    float o[10];
#pragma unroll
    for (int k = 0; k < 10; ++k) o[k] = 0.f;
    for (int c = 0; c < 64; ++c) {
        float y = sb1[c];
#pragma unroll
        for (int k = 0; k < 10; ++k) y = fmaf(ax[k], sW1[k * 64 + c], y);
        y = fmaxf(y, 0.f);
#pragma unroll
        for (int k = 0; k < 10; ++k) o[k] = fmaf(y, sW2[c * 10 + k], o[k]);
    }
#pragma unroll
    for (int k = 0; k < 10; ++k) t[i * 10 + k] = o[k] * di;
}

// v = dinv*agg2 + b2 ; out = log_softmax(v)
__global__ void final_kernel(const float* __restrict__ agg2, const float* __restrict__ dinv,
                             const float* __restrict__ b2, float* __restrict__ out, int N) {
    int i = blockIdx.x * blockDim.x + threadIdx.x;
    if (i >= N) return;
    float di = dinv[i];
    float v[10];
    float m = -1e30f;
#pragma unroll
    for (int c = 0; c < 10; ++c) {
        float u = di * agg2[i * 10 + c] + b2[c];
        v[c] = u;
        m = fmaxf(m, u);
    }
    float s = 0.f;
#pragma unroll
    for (int c = 0; c < 10; ++c) s += __expf(v[c] - m);
    float lse = __logf(s);
#pragma unroll
    for (int c = 0; c < 10; ++c) out[i * 10 + c] = v[c] - m - lse;
}

extern "C" void kernel_launch(void* const* d_in, const int* in_sizes, int n_in,
                              void* d_out, int out_size, void* d_ws, size_t ws_size,
                              hipStream_t stream) {
    const float* x  = (const float*)d_in[0];
    const int*   ei = (const int*)d_in[1];
    const float* W1 = (const float*)d_in[2];
    const float* b1 = (const float*)d_in[3];
    const float* W2 = (const float*)d_in[4];
    const float* b2 = (const float*)d_in[5];
    float* out = (float*)d_out;

    const int N = N_NODES, E = N_EDGES;
    const int* src = ei;
    const int* dst = ei + E;

    // ws: [tail 512 ints][pairs NB*PCAP][cnt N][slist N*CAP][dinv N][xs N*10][agg N*10][t N*10][agg2 N*10]
    int*   tail  = (int*)d_ws;
    int*   pairs = tail + 512;
    int*   cnt   = pairs + (size_t)NB * PCAP;
    int*   slist = cnt + N;
    float* dinv  = (float*)(slist + (size_t)N * CAP);
    float* xs    = dinv + N;
    float* agg   = xs   + (size_t)N * 10;
    float* t     = agg  + (size_t)N * 10;
    float* agg2  = t    + (size_t)N * 10;

    hipMemsetAsync(tail, 0, sizeof(int) * NB, stream);

    bucket_kernel<<<ABLK, 256, 0, stream>>>(src, dst, tail, pairs, E);
    csr_kernel<<<NB, 1024, 0, stream>>>(tail, pairs, cnt, slist, N);
    dinv_xs_kernel<<<(N + 255) / 256, 256, 0, stream>>>(x, cnt, dinv, xs, N);
    agg_kernel<<<(int)(((size_t)N * 10 + 255) / 256), 256, 0, stream>>>(xs, cnt, slist, agg, N);
    layer12_kernel<<<(N + 255) / 256, 256, 0, stream>>>(agg, dinv, W1, b1, W2, t, N);
    agg_kernel<<<(int)(((size_t)N * 10 + 255) / 256), 256, 0, stream>>>(t, cnt, slist, agg2, N);
    final_kernel<<<(N + 255) / 256, 256, 0, stream>>>(agg2, dinv, b2, out, N);
}

// Round 6
// 107.726 us; speedup vs baseline: 2.7680x; 1.1364x over previous
//
#include <hip/hip_runtime.h>

#define N_NODES 100000
#define N_EDGES 1600000

#define NPB   256                      // nodes per bucket
#define NB    391                      // ceil(100000/256)
#define PCAP  8192                     // pairs capacity per bucket
#define SCAP  32                       // LDS staging slots per bucket
#define ABLK  256                      // phase-A blocks
#define BATCH 4096                     // edges per block-iteration in phase A
#define CAP   64                       // per-node CSR row capacity

// ---------------- Phase A: bucket edges with line-granular flushes ----------------
// pair = (src<<8) | (dst & 255); bucket = dst >> 8; sentinel = -1
__global__ __launch_bounds__(1024) void bucket_kernel(
    const int* __restrict__ src, const int* __restrict__ dst,
    int* __restrict__ tail, int* __restrict__ pairs, int E) {
    __shared__ int lcnt[NB];
    __shared__ int stage[NB * SCAP];
    const int tid = threadIdx.x;
    for (int b = tid; b < NB; b += 1024) lcnt[b] = 0;
    __syncthreads();

    const int chunk = (E + gridDim.x - 1) / gridDim.x;
    const int e0 = blockIdx.x * chunk;
    const int e1 = min(e0 + chunk, E);

    for (int be = e0; be < e1; be += BATCH) {
#pragma unroll
        for (int q = 0; q < 4; ++q) {
            int e = be + q * 1024 + tid;
            if (e < e1) {
                int d = dst[e];
                int p = (src[e] << 8) | (d & 255);
                int b = d >> 8;
                int pos = atomicAdd(&lcnt[b], 1);
                if (pos < SCAP) {
                    stage[b * SCAP + pos] = p;
                } else {
                    // overflow fallback: grab a full aligned group, pad with sentinels
                    int g = atomicAdd(&tail[b], 8);
                    if (g + 8 <= PCAP) {
                        pairs[b * PCAP + g] = p;
                        for (int j = 1; j < 8; ++j) pairs[b * PCAP + g + j] = -1;
                    }
                }
            }
        }
        __syncthreads();
        // flush full groups of 8 (32B aligned; each line chunk owned by this block)
        for (int b = tid; b < NB; b += 1024) {
            int n = min(lcnt[b], SCAP);
            int ng = n >> 3;
            if (ng) {
                int base = atomicAdd(&tail[b], ng * 8);
                int4* gdst = (int4*)(pairs + b * PCAP + base);
                int4* lsrc = (int4*)(stage + b * SCAP);
                for (int g = 0; g < ng; ++g) {
                    if (base + g * 8 + 8 <= PCAP) {
                        gdst[g * 2]     = lsrc[g * 2];
                        gdst[g * 2 + 1] = lsrc[g * 2 + 1];
                    }
                }
                int rem = n & 7;
                for (int j = 0; j < rem; ++j) stage[b * SCAP + j] = stage[b * SCAP + ng * 8 + j];
                lcnt[b] = rem;
            } else {
                lcnt[b] = n;
            }
        }
        __syncthreads();
    }
    // final flush: pad remainder to a full group with sentinels
    for (int b = tid; b < NB; b += 1024) {
        int n = min(lcnt[b], SCAP);
        if (n) {
            int ng = (n + 7) >> 3;
            for (int j = n; j < ng * 8; ++j) stage[b * SCAP + j] = -1;
            int base = atomicAdd(&tail[b], ng * 8);
            int4* gdst = (int4*)(pairs + b * PCAP + base);
            int4* lsrc = (int4*)(stage + b * SCAP);
            for (int g = 0; g < ng; ++g) {
                if (base + g * 8 + 8 <= PCAP) {
                    gdst[g * 2]     = lsrc[g * 2];
                    gdst[g * 2 + 1] = lsrc[g * 2 + 1];
                }
            }
        }
    }
}

// ---------------- Phase B: pairs -> CSR rows + fused dinv/xs12 ----------------
// slist[node*CAP+pos] = src ; rows padded to mult-of-4 with N_NODES (the zero row);
// also emits dinv and xs12 (x * dinv, 12-stride), and zeroes xs12/t12 row N.
__global__ __launch_bounds__(1024) void csr_kernel(
    const int* __restrict__ tail, const int* __restrict__ pairs,
    const float* __restrict__ x, int* __restrict__ cnt, int* __restrict__ slist,
    float* __restrict__ dinv, float* __restrict__ xs12, float* __restrict__ t12, int N) {
    __shared__ int ofs[NPB];
    const int b = blockIdx.x, tid = threadIdx.x;
    if (tid < NPB) ofs[tid] = 0;
    __syncthreads();
    const int n = min(tail[b], PCAP);
    const int* pb = pairs + b * PCAP;
    const int node0 = b * NPB;
    for (int i = tid; i < n; i += 1024) {
        int p = pb[i];
        if (p >= 0) {
            int dl = p & 255;
            int pos = atomicAdd(&ofs[dl], 1);
            if (pos < CAP) slist[(size_t)(node0 + dl) * CAP + pos] = p >> 8;
        }
    }
    __syncthreads();
    if (tid < NPB) {
        int node = node0 + tid;
        if (node < N) {
            int deg = min(ofs[tid], CAP);
            cnt[node] = deg;
            int padded = (deg + 3) & ~3;
            for (int j = deg; j < padded; ++j) slist[(size_t)node * CAP + j] = N_NODES;
            float di = rsqrtf((float)deg + 1.0f);
            dinv[node] = di;
#pragma unroll
            for (int k = 0; k < 10; ++k) xs12[(size_t)node * 12 + k] = x[(size_t)node * 10 + k] * di;
            xs12[(size_t)node * 12 + 10] = 0.f;
            xs12[(size_t)node * 12 + 11] = 0.f;
        }
    }
    if (b == 0 && tid == 0) {   // zero row N of both gather tables
#pragma unroll
        for (int k = 0; k < 12; ++k) { xs12[(size_t)N * 12 + k] = 0.f; t12[(size_t)N * 12 + k] = 0.f; }
    }
}

// ---------------- gather-aggregate: 3 threads/node, float4 per edge ----------------
// out12[i][cg*4..] = val12[i][..] (self) + sum_{s in in(i)} val12[s][..]
__global__ void agg_kernel(const float* __restrict__ val12, const int* __restrict__ cnt,
                           const int* __restrict__ slist, float* __restrict__ out12, int N) {
    int gt = blockIdx.x * blockDim.x + threadIdx.x;
    int i = gt / 3;
    int cg = gt - i * 3;
    if (i >= N) return;
    int degi = cnt[i];
    const int* lst = slist + (size_t)i * CAP;
    float4 a = ((const float4*)(val12 + (size_t)i * 12))[cg];
    for (int k = 0; k < degi; k += 4) {
        int4 s4 = *reinterpret_cast<const int4*>(lst + k);
        float4 v0 = ((const float4*)(val12 + (size_t)s4.x * 12))[cg];
        float4 v1 = ((const float4*)(val12 + (size_t)s4.y * 12))[cg];
        float4 v2 = ((const float4*)(val12 + (size_t)s4.z * 12))[cg];
        float4 v3 = ((const float4*)(val12 + (size_t)s4.w * 12))[cg];
        a.x += v0.x + v1.x + v2.x + v3.x;
        a.y += v0.y + v1.y + v2.y + v3.y;
        a.z += v0.z + v1.z + v2.z + v3.z;
        a.w += v0.w + v1.w + v2.w + v3.w;
    }
    ((float4*)(out12 + (size_t)i * 12))[cg] = a;
}

// ---------------- fused MLP: ax = dinv*agg ; y = relu(ax@W1+b1) ; t12 = (y@W2)*dinv ----------------
__global__ void layer12_kernel(const float* __restrict__ agg12, const float* __restrict__ dinv,
                               const float* __restrict__ W1, const float* __restrict__ b1,
                               const float* __restrict__ W2, float* __restrict__ t12, int N) {
    __shared__ float sW1[640];
    __shared__ float sW2[640];
    __shared__ float sb1[64];
    for (int k = threadIdx.x; k < 640; k += blockDim.x) { sW1[k] = W1[k]; sW2[k] = W2[k]; }
    if (threadIdx.x < 64) sb1[threadIdx.x] = b1[threadIdx.x];
    __syncthreads();
    int i = blockIdx.x * blockDim.x + threadIdx.x;
    if (i >= N) return;
    float di = dinv[i];
    float ax[10];
#pragma unroll
    for (int k = 0; k < 10; ++k) ax[k] = di * agg12[(size_t)i * 12 + k];
    float o[10];
#pragma unroll
    for (int k = 0; k < 10; ++k) o[k] = 0.f;
    for (int c = 0; c < 64; ++c) {
        float y = sb1[c];
#pragma unroll
        for (int k = 0; k < 10; ++k) y = fmaf(ax[k], sW1[k * 64 + c], y);
        y = fmaxf(y, 0.f);
#pragma unroll
        for (int k = 0; k < 10; ++k) o[k] = fmaf(y, sW2[c * 10 + k], o[k]);
    }
#pragma unroll
    for (int k = 0; k < 10; ++k) t12[(size_t)i * 12 + k] = o[k] * di;
    t12[(size_t)i * 12 + 10] = 0.f;
    t12[(size_t)i * 12 + 11] = 0.f;
}

// ---------------- final: v = dinv*agg2 + b2 ; out = log_softmax(v) ----------------
__global__ void final_kernel(const float* __restrict__ agg2_12, const float* __restrict__ dinv,
                             const float* __restrict__ b2, float* __restrict__ out, int N) {
    int i = blockIdx.x * blockDim.x + threadIdx.x;
    if (i >= N) return;
    float di = dinv[i];
    float v[10];
    float m = -1e30f;
#pragma unroll
    for (int c = 0; c < 10; ++c) {
        float u = di * agg2_12[(size_t)i * 12 + c] + b2[c];
        v[c] = u;
        m = fmaxf(m, u);
    }
    float s = 0.f;
#pragma unroll
    for (int c = 0; c < 10; ++c) s += __expf(v[c] - m);
    float lse = __logf(s);
#pragma unroll
    for (int c = 0; c < 10; ++c) out[(size_t)i * 10 + c] = v[c] - m - lse;
}

extern "C" void kernel_launch(void* const* d_in, const int* in_sizes, int n_in,
                              void* d_out, int out_size, void* d_ws, size_t ws_size,
                              hipStream_t stream) {
    const float* x  = (const float*)d_in[0];
    const int*   ei = (const int*)d_in[1];
    const float* W1 = (const float*)d_in[2];
    const float* b1 = (const float*)d_in[3];
    const float* W2 = (const float*)d_in[4];
    const float* b2 = (const float*)d_in[5];
    float* out = (float*)d_out;

    const int N = N_NODES, E = N_EDGES;
    const int* src = ei;
    const int* dst = ei + E;

    // ws: [tail 512i][pairs NB*PCAP][cnt N][slist N*CAP][dinv N][xs12 (N+1)*12][agg12 (N+1)*12]
    //     [t12 (N+1)*12][agg2 (N+1)*12]   (all 16B-aligned)
    int*   tail  = (int*)d_ws;
    int*   pairs = tail + 512;
    int*   cnt   = pairs + (size_t)NB * PCAP;
    int*   slist = cnt + N;
    float* dinv  = (float*)(slist + (size_t)N * CAP);
    float* xs12  = dinv + N;
    float* agg12 = xs12 + (size_t)(N + 1) * 12;
    float* t12   = agg12 + (size_t)(N + 1) * 12;
    float* agg2  = t12   + (size_t)(N + 1) * 12;

    hipMemsetAsync(tail, 0, sizeof(int) * NB, stream);

    bucket_kernel<<<ABLK, 1024, 0, stream>>>(src, dst, tail, pairs, E);
    csr_kernel<<<NB, 1024, 0, stream>>>(tail, pairs, x, cnt, slist, dinv, xs12, t12, N);
    agg_kernel<<<(int)(((size_t)N * 3 + 255) / 256), 256, 0, stream>>>(xs12, cnt, slist, agg12, N);
    layer12_kernel<<<(N + 255) / 256, 256, 0, stream>>>(agg12, dinv, W1, b1, W2, t12, N);
    agg_kernel<<<(int)(((size_t)N * 3 + 255) / 256), 256, 0, stream>>>(t12, cnt, slist, agg2, N);
    final_kernel<<<(N + 255) / 256, 256, 0, stream>>>(agg2, dinv, b2, out, N);
}

// Round 7
// 105.277 us; speedup vs baseline: 2.8324x; 1.0233x over previous
//
#include <hip/hip_runtime.h>

#define N_NODES 100000
#define N_EDGES 1600000

#define NPB   256                      // nodes per bucket
#define NB    391                      // ceil(100000/256)
#define PCAP  8192                     // pairs capacity per bucket
#define SCAP  32                       // LDS staging slots per bucket
#define ABLK  256                      // phase-A blocks
#define BATCH 4096                     // edges per block-iteration in phase A
#define CAP   64                       // per-node CSR row capacity

// zero the tail counters on the compute queue (hipMemsetAsync's graph node cost ~40us)
__global__ void zero_tail_kernel(int* __restrict__ tail) {
    tail[threadIdx.x] = 0;
}

// ---------------- Phase A: bucket edges with line-granular flushes ----------------
// pair = (src<<8) | (dst & 255); bucket = dst >> 8; sentinel = -1
__global__ __launch_bounds__(1024) void bucket_kernel(
    const int* __restrict__ src, const int* __restrict__ dst,
    int* __restrict__ tail, int* __restrict__ pairs, int E) {
    __shared__ int lcnt[NB];
    __shared__ int stage[NB * SCAP];
    const int tid = threadIdx.x;
    for (int b = tid; b < NB; b += 1024) lcnt[b] = 0;
    __syncthreads();

    const int chunk = (E + gridDim.x - 1) / gridDim.x;
    const int e0 = blockIdx.x * chunk;
    const int e1 = min(e0 + chunk, E);

    for (int be = e0; be < e1; be += BATCH) {
#pragma unroll
        for (int q = 0; q < 4; ++q) {
            int e = be + q * 1024 + tid;
            if (e < e1) {
                int d = dst[e];
                int p = (src[e] << 8) | (d & 255);
                int b = d >> 8;
                int pos = atomicAdd(&lcnt[b], 1);
                if (pos < SCAP) {
                    stage[b * SCAP + pos] = p;
                } else {
                    // overflow fallback: grab a full aligned group, pad with sentinels
                    int g = atomicAdd(&tail[b], 8);
                    if (g + 8 <= PCAP) {
                        pairs[b * PCAP + g] = p;
                        for (int j = 1; j < 8; ++j) pairs[b * PCAP + g + j] = -1;
                    }
                }
            }
        }
        __syncthreads();
        // flush full groups of 8 (32B aligned; each line chunk owned by this block)
        for (int b = tid; b < NB; b += 1024) {
            int n = min(lcnt[b], SCAP);
            int ng = n >> 3;
            if (ng) {
                int base = atomicAdd(&tail[b], ng * 8);
                int4* gdst = (int4*)(pairs + b * PCAP + base);
                int4* lsrc = (int4*)(stage + b * SCAP);
                for (int g = 0; g < ng; ++g) {
                    if (base + g * 8 + 8 <= PCAP) {
                        gdst[g * 2]     = lsrc[g * 2];
                        gdst[g * 2 + 1] = lsrc[g * 2 + 1];
                    }
                }
                int rem = n & 7;
                for (int j = 0; j < rem; ++j) stage[b * SCAP + j] = stage[b * SCAP + ng * 8 + j];
                lcnt[b] = rem;
            } else {
                lcnt[b] = n;
            }
        }
        __syncthreads();
    }
    // final flush: pad remainder to a full group with sentinels
    for (int b = tid; b < NB; b += 1024) {
        int n = min(lcnt[b], SCAP);
        if (n) {
            int ng = (n + 7) >> 3;
            for (int j = n; j < ng * 8; ++j) stage[b * SCAP + j] = -1;
            int base = atomicAdd(&tail[b], ng * 8);
            int4* gdst = (int4*)(pairs + b * PCAP + base);
            int4* lsrc = (int4*)(stage + b * SCAP);
            for (int g = 0; g < ng; ++g) {
                if (base + g * 8 + 8 <= PCAP) {
                    gdst[g * 2]     = lsrc[g * 2];
                    gdst[g * 2 + 1] = lsrc[g * 2 + 1];
                }
            }
        }
    }
}

// ---------------- Phase B: pairs -> CSR rows + fused dinv/xs12 ----------------
// slist[node*CAP+pos] = src ; rows padded to mult-of-4 with N_NODES (the zero row);
// also emits dinv and xs12 (x * dinv, 12-stride), and zeroes xs12/t12 row N.
__global__ __launch_bounds__(1024) void csr_kernel(
    const int* __restrict__ tail, const int* __restrict__ pairs,
    const float* __restrict__ x, int* __restrict__ cnt, int* __restrict__ slist,
    float* __restrict__ dinv, float* __restrict__ xs12, float* __restrict__ t12, int N) {
    __shared__ int ofs[NPB];
    const int b = blockIdx.x, tid = threadIdx.x;
    if (tid < NPB) ofs[tid] = 0;
    __syncthreads();
    const int n = min(tail[b], PCAP);
    const int* pb = pairs + b * PCAP;
    const int node0 = b * NPB;
    for (int i = tid; i < n; i += 1024) {
        int p = pb[i];
        if (p >= 0) {
            int dl = p & 255;
            int pos = atomicAdd(&ofs[dl], 1);
            if (pos < CAP) slist[(size_t)(node0 + dl) * CAP + pos] = p >> 8;
        }
    }
    __syncthreads();
    if (tid < NPB) {
        int node = node0 + tid;
        if (node < N) {
            int deg = min(ofs[tid], CAP);
            cnt[node] = deg;
            int padded = (deg + 3) & ~3;
            for (int j = deg; j < padded; ++j) slist[(size_t)node * CAP + j] = N_NODES;
            float di = rsqrtf((float)deg + 1.0f);
            dinv[node] = di;
#pragma unroll
            for (int k = 0; k < 10; ++k) xs12[(size_t)node * 12 + k] = x[(size_t)node * 10 + k] * di;
            xs12[(size_t)node * 12 + 10] = 0.f;
            xs12[(size_t)node * 12 + 11] = 0.f;
        }
    }
    if (b == 0 && tid == 0) {   // zero row N of both gather tables
#pragma unroll
        for (int k = 0; k < 12; ++k) { xs12[(size_t)N * 12 + k] = 0.f; t12[(size_t)N * 12 + k] = 0.f; }
    }
}

// ---------------- gather-aggregate: 3 threads/node, float4 per edge ----------------
// out12[i][cg*4..] = val12[i][..] (self) + sum_{s in in(i)} val12[s][..]
__global__ void agg_kernel(const float* __restrict__ val12, const int* __restrict__ cnt,
                           const int* __restrict__ slist, float* __restrict__ out12, int N) {
    int gt = blockIdx.x * blockDim.x + threadIdx.x;
    int i = gt / 3;
    int cg = gt - i * 3;
    if (i >= N) return;
    int degi = cnt[i];
    const int* lst = slist + (size_t)i * CAP;
    float4 a = ((const float4*)(val12 + (size_t)i * 12))[cg];
    for (int k = 0; k < degi; k += 4) {
        int4 s4 = *reinterpret_cast<const int4*>(lst + k);
        float4 v0 = ((const float4*)(val12 + (size_t)s4.x * 12))[cg];
        float4 v1 = ((const float4*)(val12 + (size_t)s4.y * 12))[cg];
        float4 v2 = ((const float4*)(val12 + (size_t)s4.z * 12))[cg];
        float4 v3 = ((const float4*)(val12 + (size_t)s4.w * 12))[cg];
        a.x += v0.x + v1.x + v2.x + v3.x;
        a.y += v0.y + v1.y + v2.y + v3.y;
        a.z += v0.z + v1.z + v2.z + v3.z;
        a.w += v0.w + v1.w + v2.w + v3.w;
    }
    ((float4*)(out12 + (size_t)i * 12))[cg] = a;
}

// ---------------- fused MLP: ax = dinv*agg ; y = relu(ax@W1+b1) ; t12 = (y@W2)*dinv ----------------
__global__ void layer12_kernel(const float* __restrict__ agg12, const float* __restrict__ dinv,
                               const float* __restrict__ W1, const float* __restrict__ b1,
                               const float* __restrict__ W2, float* __restrict__ t12, int N) {
    __shared__ float sW1[640];
    __shared__ float sW2[640];
    __shared__ float sb1[64];
    for (int k = threadIdx.x; k < 640; k += blockDim.x) { sW1[k] = W1[k]; sW2[k] = W2[k]; }
    if (threadIdx.x < 64) sb1[threadIdx.x] = b1[threadIdx.x];
    __syncthreads();
    int i = blockIdx.x * blockDim.x + threadIdx.x;
    if (i >= N) return;
    float di = dinv[i];
    float ax[10];
#pragma unroll
    for (int k = 0; k < 10; ++k) ax[k] = di * agg12[(size_t)i * 12 + k];
    float o[10];
#pragma unroll
    for (int k = 0; k < 10; ++k) o[k] = 0.f;
    for (int c = 0; c < 64; ++c) {
        float y = sb1[c];
#pragma unroll
        for (int k = 0; k < 10; ++k) y = fmaf(ax[k], sW1[k * 64 + c], y);
        y = fmaxf(y, 0.f);
#pragma unroll
        for (int k = 0; k < 10; ++k) o[k] = fmaf(y, sW2[c * 10 + k], o[k]);
    }
#pragma unroll
    for (int k = 0; k < 10; ++k) t12[(size_t)i * 12 + k] = o[k] * di;
    t12[(size_t)i * 12 + 10] = 0.f;
    t12[(size_t)i * 12 + 11] = 0.f;
}

// ---------------- final: v = dinv*agg2 + b2 ; out = log_softmax(v) ----------------
__global__ void final_kernel(const float* __restrict__ agg2_12, const float* __restrict__ dinv,
                             const float* __restrict__ b2, float* __restrict__ out, int N) {
    int i = blockIdx.x * blockDim.x + threadIdx.x;
    if (i >= N) return;
    float di = dinv[i];
    float v[10];
    float m = -1e30f;
#pragma unroll
    for (int c = 0; c < 10; ++c) {
        float u = di * agg2_12[(size_t)i * 12 + c] + b2[c];
        v[c] = u;
        m = fmaxf(m, u);
    }
    float s = 0.f;
#pragma unroll
    for (int c = 0; c < 10; ++c) s += __expf(v[c] - m);
    float lse = __logf(s);
#pragma unroll
    for (int c = 0; c < 10; ++c) out[(size_t)i * 10 + c] = v[c] - m - lse;
}

extern "C" void kernel_launch(void* const* d_in, const int* in_sizes, int n_in,
                              void* d_out, int out_size, void* d_ws, size_t ws_size,
                              hipStream_t stream) {
    const float* x  = (const float*)d_in[0];
    const int*   ei = (const int*)d_in[1];
    const float* W1 = (const float*)d_in[2];
    const float* b1 = (const float*)d_in[3];
    const float* W2 = (const float*)d_in[4];
    const float* b2 = (const float*)d_in[5];
    float* out = (float*)d_out;

    const int N = N_NODES, E = N_EDGES;
    const int* src = ei;
    const int* dst = ei + E;

    // ws: [tail 512i][pairs NB*PCAP][cnt N][slist N*CAP][dinv N][xs12 (N+1)*12][agg12 (N+1)*12]
    //     [t12 (N+1)*12][agg2 (N+1)*12]   (all 16B-aligned)
    int*   tail  = (int*)d_ws;
    int*   pairs = tail + 512;
    int*   cnt   = pairs + (size_t)NB * PCAP;
    int*   slist = cnt + N;
    float* dinv  = (float*)(slist + (size_t)N * CAP);
    float* xs12  = dinv + N;
    float* agg12 = xs12 + (size_t)(N + 1) * 12;
    float* t12   = agg12 + (size_t)(N + 1) * 12;
    float* agg2  = t12   + (size_t)(N + 1) * 12;

    zero_tail_kernel<<<1, 512, 0, stream>>>(tail);
    bucket_kernel<<<ABLK, 1024, 0, stream>>>(src, dst, tail, pairs, E);
    csr_kernel<<<NB, 1024, 0, stream>>>(tail, pairs, x, cnt, slist, dinv, xs12, t12, N);
    agg_kernel<<<(int)(((size_t)N * 3 + 255) / 256), 256, 0, stream>>>(xs12, cnt, slist, agg12, N);
    layer12_kernel<<<(N + 255) / 256, 256, 0, stream>>>(agg12, dinv, W1, b1, W2, t12, N);
    agg_kernel<<<(int)(((size_t)N * 3 + 255) / 256), 256, 0, stream>>>(t12, cnt, slist, agg2, N);
    final_kernel<<<(N + 255) / 256, 256, 0, stream>>>(agg2, dinv, b2, out, N);
}